// Round 11
// baseline (541.974 us; speedup 1.0000x reference)
//
#include <hip/hip_runtime.h>
#include <math.h>

#define N_NODES 20000
#define N_EDGES 320000
#define EMB 128
#define HID 512          // 4*EMB
#define ROWS_PER_BLOCK 16
#define SC_CAP 2048      // LDS score cache per block
#define NCHUNK ((N_NODES + 1023) / 1024)   // 20

typedef float v2f __attribute__((ext_vector_type(2)));

#if defined(__has_builtin)
#if __has_builtin(__builtin_elementwise_fma)
#define V2FMA(a, b, c) __builtin_elementwise_fma((a), (b), (c))
#else
#define V2FMA(a, b, c) ((a) * (b) + (c))
#endif
#else
#define V2FMA(a, b, c) ((a) * (b) + (c))
#endif

// ---------------------------------------------------------------------------
__global__ void init_deg(int* __restrict__ deg, int* __restrict__ offs) {
    int i = blockIdx.x * 256 + threadIdx.x;
    if (i < N_NODES) deg[i] = 0;
    if (i == 0) offs[N_NODES] = N_EDGES;
}

// ---------------------------------------------------------------------------
// K2: heterogeneous blocks — [0,GEMM_BLOCKS) = GEMM, rest = row histogram.
//
// GEMM REWRITE (the old 128x128 LDS-tiled version was LDS-data-bound:
// 2.6 GB of ds_read_b128 at ~85 B/cyc/CU ≈ 50 µs floor, ~110 µs measured).
// New structure: ZERO LDS, zero barriers.
//   wave = 64 rows x 64 cols; lane = row.
//   A: per-lane global reads of h[row][k] (full-row use, L2/L3 resident).
//   B: wave-UNIFORM address W1[k][c0+j] -> scalar s_load into SGPRs on the
//      independent SMEM pipe (or L1-broadcast vector loads — either is fine).
//   acc: 64 f32 (32 v2f) in VGPRs, v_pk_fma.
// ---------------------------------------------------------------------------
#define GX 4                                 // col groups of 256 (4*256=1024)
#define GY ((N_NODES + 63) / 64)             // 313 row tiles of 64
#define GEMM_BLOCKS (GX * GY)                // 1252
#define HIST_BLOCKS ((N_EDGES + 255) / 256)  // 1250

__global__ __launch_bounds__(256) void gemm_hist(
    const float* __restrict__ h, const float* __restrict__ W1,
    const float* __restrict__ b1, float* __restrict__ P, float* __restrict__ Q,
    const int* __restrict__ row, int* __restrict__ deg)
{
    const int bid = blockIdx.x;
    const int tid = threadIdx.x;

    if (bid >= GEMM_BLOCKS) {
        // ---- histogram path ----
        const int e = (bid - GEMM_BLOCKS) * 256 + tid;
        if (e < N_EDGES) atomicAdd(&deg[row[e]], 1);
        return;
    }

    // ---- gemm path ----
    const int bx = bid & 3;            // 0..3 (col group of 256)
    const int by = bid >> 2;           // 0..312 (row tile of 64)
    const int w  = tid >> 6;           // wave 0..3
    const int lane = tid & 63;

    const int g0  = bx * 256 + w * 64;           // global col base (wave-uniform)
    const bool isP = (g0 < HID);
    const int w_off = isP ? 0 : EMB;             // W1 row offset (P vs Q half)
    const int c0    = isP ? g0 : g0 - HID;       // col within P/Q
    const float* __restrict__ wbase = W1 + (size_t)w_off * HID + c0;

    const int  r   = by * 64 + lane;
    const bool rok = r < N_NODES;
    const float* __restrict__ hrow = h + (size_t)(rok ? r : 0) * EMB;

    v2f acc[32] = {};

    float4 a4 = *(const float4*)(hrow);          // k = 0..3
    for (int k0 = 0; k0 < EMB; k0 += 4) {
        float4 a_n = a4;
        if (k0 + 4 < EMB) a_n = *(const float4*)(hrow + k0 + 4);   // prefetch
        const float av[4] = {a4.x, a4.y, a4.z, a4.w};
#pragma unroll
        for (int kk = 0; kk < 4; ++kk) {
            const float* __restrict__ wrow = wbase + (size_t)(k0 + kk) * HID;
            const v2f a2 = (v2f){av[kk], av[kk]};
#pragma unroll
            for (int j = 0; j < 32; ++j) {
                v2f b = *(const v2f*)(wrow + j * 2);   // wave-uniform -> s_load
                acc[j] = V2FMA(a2, b, acc[j]);
            }
        }
        a4 = a_n;
    }

    if (rok) {
        if (isP) {   // bias fold: P half only (uniform loads)
#pragma unroll
            for (int j = 0; j < 32; ++j) {
                v2f b = *(const v2f*)(b1 + c0 + j * 2);
                acc[j] += b;
            }
        }
        float* __restrict__ dst = (isP ? P : Q) + (size_t)r * HID + c0;
#pragma unroll
        for (int j = 0; j < 16; ++j) {
            *(float4*)(dst + j * 4) =
                make_float4(acc[2*j].x, acc[2*j].y, acc[2*j+1].x, acc[2*j+1].y);
        }
    }
}

// ---------------------------------------------------------------------------
__device__ __forceinline__ int wave_incl_scan(int v, int lane) {
#pragma unroll
    for (int off = 1; off < 64; off <<= 1) {
        int t = __shfl_up(v, off, 64);
        if (lane >= off) v += t;
    }
    return v;
}

__global__ __launch_bounds__(1024) void scan_part(const int* __restrict__ deg,
                                                  int* __restrict__ part,
                                                  int* __restrict__ totals) {
    __shared__ int wsum[16];
    const int tid = threadIdx.x, lane = tid & 63, w = tid >> 6;
    const int i = blockIdx.x * 1024 + tid;
    int v = (i < N_NODES) ? deg[i] : 0;
    int incl = wave_incl_scan(v, lane);
    if (lane == 63) wsum[w] = incl;
    __syncthreads();
    if (w == 0) {
        int x = (lane < 16) ? wsum[lane] : 0;
        int xs = wave_incl_scan(x, lane);
        if (lane < 16) wsum[lane] = xs - x;
        if (lane == 15) totals[blockIdx.x] = xs;
    }
    __syncthreads();
    if (i < N_NODES) part[i] = wsum[w] + incl - v;
}

// scan_carry folded in: every block redundantly scans the 20 chunk totals.
__global__ __launch_bounds__(1024) void scan_apply(const int* __restrict__ part,
                                                   const int* __restrict__ totals,
                                                   int* __restrict__ cursor,
                                                   int* __restrict__ offs) {
    __shared__ int carry_s;
    const int tid = threadIdx.x;
    if (tid < 64) {
        int v = (tid < NCHUNK) ? totals[tid] : 0;
        int incl = wave_incl_scan(v, tid);
        if (tid == (int)blockIdx.x) carry_s = incl - v;   // exclusive carry
    }
    __syncthreads();
    const int i = blockIdx.x * 1024 + tid;
    if (i < N_NODES) {
        int o = part[i] + carry_s;
        cursor[i] = o;
        offs[i] = o;
    }
}

// ---------------------------------------------------------------------------
// scatter: ONE int2 {e, row<<16|col} per edge (lossless: row,col < 32768)
// ---------------------------------------------------------------------------
__global__ void scatter_edges(const int* __restrict__ row, const int* __restrict__ col,
                              int* __restrict__ cursor, int2* __restrict__ rc2) {
    int e = blockIdx.x * 256 + threadIdx.x;
    if (e >= N_EDGES) return;
    int r = row[e];
    int pos = atomicAdd(&cursor[r], 1);
    rc2[pos] = make_int2(e, (r << 16) | col[e]);
}

// ---------------------------------------------------------------------------
// Fused edge phase — champion config (256 thr, RPB=16, x2 unroll; occupancy
// experiments r6/r9 both showed more waves = more thrash = slower).
// ---------------------------------------------------------------------------
__global__ __launch_bounds__(256) void fused_edge(
    const float* __restrict__ P, const float* __restrict__ Q,
    const float* __restrict__ W2, const float* __restrict__ b2,
    const int2* __restrict__ rc2, const int* __restrict__ offs,
    const float* __restrict__ u, const int* __restrict__ edge_mask,
    const int* __restrict__ hierarchy,
    float* __restrict__ scores, float* __restrict__ out_y,
    float* __restrict__ out_mask, float* __restrict__ out_causal,
    float* __restrict__ out_spu)
{
    __shared__ float sc_lds[SC_CAP];

    const int r0 = blockIdx.x * ROWS_PER_BLOCK;
    const int r1 = (r0 + ROWS_PER_BLOCK < N_NODES) ? r0 + ROWS_PER_BLOCK : N_NODES;
    const int e0 = offs[r0];
    const int e1 = offs[r1];
    const int tid = threadIdx.x, lane = tid & 63, w = tid >> 6;
    const int j0 = lane << 2;

    const float4 w0 = *(const float4*)(W2 + j0);
    const float4 w1 = *(const float4*)(W2 + 256 + j0);
    const float bias2 = b2[0];

    // ---- phase 1: scores, two edges per wave-iteration ----
    for (int i0 = e0 + (w << 1); i0 < e1; i0 += 8) {
        const int  iA   = i0;
        const bool hasB = (i0 + 1) < e1;
        const int  iB   = hasB ? i0 + 1 : i0;

        const int2 eA = rc2[iA];
        const int2 eB = rc2[iB];
        const int rA = ((unsigned)eA.y) >> 16, cA = eA.y & 0xFFFF;
        const int rB = ((unsigned)eB.y) >> 16, cB = eB.y & 0xFFFF;
        const float* __restrict__ pA = P + (size_t)rA * HID;
        const float* __restrict__ qA = Q + (size_t)cA * HID;
        const float* __restrict__ pB = P + (size_t)rB * HID;
        const float* __restrict__ qB = Q + (size_t)cB * HID;

        float4 pA0 = *(const float4*)(pA + j0);
        float4 pA1 = *(const float4*)(pA + 256 + j0);
        float4 qA0 = *(const float4*)(qA + j0);
        float4 qA1 = *(const float4*)(qA + 256 + j0);
        float4 pB0 = *(const float4*)(pB + j0);
        float4 pB1 = *(const float4*)(pB + 256 + j0);
        float4 qB0 = *(const float4*)(qB + j0);
        float4 qB1 = *(const float4*)(qB + 256 + j0);

        float sA = 0.0f, sB = 0.0f;
        sA = fmaf(fmaxf(pA0.x + qA0.x, 0.0f), w0.x, sA);
        sA = fmaf(fmaxf(pA0.y + qA0.y, 0.0f), w0.y, sA);
        sA = fmaf(fmaxf(pA0.z + qA0.z, 0.0f), w0.z, sA);
        sA = fmaf(fmaxf(pA0.w + qA0.w, 0.0f), w0.w, sA);
        sA = fmaf(fmaxf(pA1.x + qA1.x, 0.0f), w1.x, sA);
        sA = fmaf(fmaxf(pA1.y + qA1.y, 0.0f), w1.y, sA);
        sA = fmaf(fmaxf(pA1.z + qA1.z, 0.0f), w1.z, sA);
        sA = fmaf(fmaxf(pA1.w + qA1.w, 0.0f), w1.w, sA);
        sB = fmaf(fmaxf(pB0.x + qB0.x, 0.0f), w0.x, sB);
        sB = fmaf(fmaxf(pB0.y + qB0.y, 0.0f), w0.y, sB);
        sB = fmaf(fmaxf(pB0.z + qB0.z, 0.0f), w0.z, sB);
        sB = fmaf(fmaxf(pB0.w + qB0.w, 0.0f), w0.w, sB);
        sB = fmaf(fmaxf(pB1.x + qB1.x, 0.0f), w1.x, sB);
        sB = fmaf(fmaxf(pB1.y + qB1.y, 0.0f), w1.y, sB);
        sB = fmaf(fmaxf(pB1.z + qB1.z, 0.0f), w1.z, sB);
        sB = fmaf(fmaxf(pB1.w + qB1.w, 0.0f), w1.w, sB);

#pragma unroll
        for (int off = 32; off > 0; off >>= 1) {
            sA += __shfl_down(sA, off, 64);
            sB += __shfl_down(sB, off, 64);
        }

        if (lane == 0) {
            float scA = sA + bias2;
            scores[eA.x] = scA;
            int liA = iA - e0;
            if (liA < SC_CAP) sc_lds[liA] = scA;
            if (hasB) {
                float scB = sB + bias2;
                scores[eB.x] = scB;
                int liB = iB - e0;
                if (liB < SC_CAP) sc_lds[liB] = scB;
            }
        }
    }
    __syncthreads();

    // ---- phase 2: wave per row ----
    const int hv = hierarchy[0];
    for (int r = r0 + w; r < r1; r += 4) {
        const int es = offs[r], ee = offs[r + 1];
        const int d = ee - es;
        if (d == 0) continue;

        float m = -INFINITY;
        for (int j = lane; j < d; j += 64) {
            int li = es - e0 + j;
            float s = (li < SC_CAP) ? sc_lds[li] : scores[rc2[es + j].x];
            m = fmaxf(m, s);
        }
#pragma unroll
        for (int off = 32; off > 0; off >>= 1)
            m = fmaxf(m, __shfl_down(m, off, 64));
        m = __shfl(m, 0, 64);

        float ssum = 0.0f;
        for (int j = lane; j < d; j += 64) {
            int li = es - e0 + j;
            float s = (li < SC_CAP) ? sc_lds[li] : scores[rc2[es + j].x];
            ssum += expf(s - m);
        }
#pragma unroll
        for (int off = 32; off > 0; off >>= 1)
            ssum += __shfl_down(ssum, off, 64);
        ssum = __shfl(ssum, 0, 64);

        for (int j = lane; j < d; j += 64) {
            int li = es - e0 + j;
            float s = (li < SC_CAP) ? sc_lds[li] : scores[rc2[es + j].x];
            float p = expf(s - m) / ssum;
            float logits = logf(p) - log1pf(-p);   // +inf when p==1 (d==1)
            int oe = rc2[es + j].x;
            float uu = u[oe];
            float L = logf(uu) - log1pf(-uu);
            float y = 1.0f / (1.0f + expf(-(logits + L)));
            bool hard = y > 0.5f;                  // ST forward value == y_hard
            int mm = hard ? (hv + 1) : edge_mask[oe];
            out_y[oe]      = hard ? 1.0f : 0.0f;
            out_mask[oe]   = (float)mm;
            out_causal[oe] = (mm > 0)   ?  s : 0.0f;
            out_spu[oe]    = (mm == -1) ? -s : 0.0f;
        }
    }
}

// ---------------------------------------------------------------------------
extern "C" void kernel_launch(void* const* d_in, const int* in_sizes, int n_in,
                              void* d_out, int out_size, void* d_ws, size_t ws_size,
                              hipStream_t stream) {
    const float* h_ptr = (const float*)d_in[0];
    const float* W1    = (const float*)d_in[1];
    const float* b1    = (const float*)d_in[2];
    const float* W2    = (const float*)d_in[3];
    const float* b2    = (const float*)d_in[4];
    const float* u     = (const float*)d_in[5];
    const int*   row   = (const int*)d_in[6];
    const int*   col   = (const int*)d_in[7];
    const int*   emask = (const int*)d_in[8];
    const int*   hier  = (const int*)d_in[9];

    float* out        = (float*)d_out;
    float* scores     = out;                        // [E]
    float* out_y      = out + (size_t)N_EDGES;      // [E]
    float* out_mask   = out + 2 * (size_t)N_EDGES;  // [E]
    float* out_causal = out + 3 * (size_t)N_EDGES;  // [E]
    float* out_spu    = out + 4 * (size_t)N_EDGES;  // [E]

    // workspace (4B units): P, Q first (16B align), rc2 (8B align), then ints
    float* P      = (float*)d_ws;
    float* Qm     = P + (size_t)N_NODES * HID;
    int2*  rc2    = (int2*)(Qm + (size_t)N_NODES * HID);   // [E] int2
    int*   deg    = (int*)(rc2 + N_EDGES);
    int*   cursor = deg + N_NODES;
    int*   offs   = cursor + N_NODES;               // [N_NODES+1]
    int*   part   = offs + N_NODES + 1;
    int*   totals = part + N_NODES;                 // [NCHUNK]

    hipLaunchKernelGGL(init_deg, dim3((N_NODES + 255) / 256), dim3(256), 0, stream,
                       deg, offs);

    hipLaunchKernelGGL(gemm_hist, dim3(GEMM_BLOCKS + HIST_BLOCKS), dim3(256), 0, stream,
                       h_ptr, W1, b1, P, Qm, row, deg);

    hipLaunchKernelGGL(scan_part, dim3(NCHUNK), dim3(1024), 0, stream, deg, part, totals);
    hipLaunchKernelGGL(scan_apply, dim3(NCHUNK), dim3(1024), 0, stream,
                       part, totals, cursor, offs);
    hipLaunchKernelGGL(scatter_edges, dim3((N_EDGES + 255) / 256), dim3(256), 0, stream,
                       row, col, cursor, rc2);

    hipLaunchKernelGGL(fused_edge, dim3((N_NODES + ROWS_PER_BLOCK - 1) / ROWS_PER_BLOCK),
                       dim3(256), 0, stream,
                       P, Qm, W2, b2, rc2, offs, u, emask, hier,
                       scores, out_y, out_mask, out_causal, out_spu);
}

// Round 12
// 332.100 us; speedup vs baseline: 1.6320x; 1.6320x over previous
//
#include <hip/hip_runtime.h>
#include <math.h>

#define N_NODES 20000
#define N_EDGES 320000
#define EMB 128
#define HID 512          // 4*EMB
#define ROWS_PER_BLOCK 16
#define SC_CAP 2048      // LDS score cache per block
#define NCHUNK ((N_NODES + 1023) / 1024)   // 20

typedef float v2f __attribute__((ext_vector_type(2)));

#if defined(__has_builtin)
#if __has_builtin(__builtin_elementwise_fma)
#define V2FMA(a, b, c) __builtin_elementwise_fma((a), (b), (c))
#else
#define V2FMA(a, b, c) ((a) * (b) + (c))
#endif
#else
#define V2FMA(a, b, c) ((a) * (b) + (c))
#endif

// ---------------------------------------------------------------------------
__global__ void init_deg(int* __restrict__ deg, int* __restrict__ offs) {
    int i = blockIdx.x * 256 + threadIdx.x;
    if (i < N_NODES) deg[i] = 0;
    if (i == 0) offs[N_NODES] = N_EDGES;
}

// ---------------------------------------------------------------------------
// K2: heterogeneous blocks — [0,GEMM_BLOCKS) = GEMM, rest = row histogram.
//
// GEMM: LDS-tiled (r11's no-LDS variant was VMEM-issue-bound: per-lane
// same-address loads do NOT become s_load — 357us). The r10 8x8-micro
// version was LDS-pipe-bound (~2.6M wave ds_read_b128 ≈ 50us floor).
// This version: 8x16 micro, 128x256 block tile -> 6 ds_read_b128 per
// 128 FMA -> 1.93M wave-reads ≈ 37us LDS floor, VALU 17us.
// BK=8 double-buffer, one barrier per K-tile.
// ---------------------------------------------------------------------------
#define TM 128
#define TN 256
#define BK 8
#define NTILES (EMB / BK)                    // 16
#define GEMM_MT ((N_NODES + TM - 1) / TM)    // 157
#define GEMM_BLOCKS (4 * GEMM_MT)            // 628 (4 col tiles of 256)
#define HIST_BLOCKS ((N_EDGES + 255) / 256)  // 1250

__global__ __launch_bounds__(256) void gemm_hist(
    const float* __restrict__ h, const float* __restrict__ W1,
    const float* __restrict__ b1, float* __restrict__ P, float* __restrict__ Q,
    const int* __restrict__ row, int* __restrict__ deg)
{
    const int bid = blockIdx.x;
    const int tid = threadIdx.x;

    if (bid >= GEMM_BLOCKS) {
        // ---- histogram path ----
        const int e = (bid - GEMM_BLOCKS) * 256 + tid;
        if (e < N_EDGES) atomicAdd(&deg[row[e]], 1);
        return;
    }

    // ---- gemm path ----
    __shared__ float As[2][BK][TM + 4];   // transposed A, stride 132
    __shared__ float Bs[2][BK][TN];

    const int nt = bid & 3;        // 0..3 (628 = 4*157 exactly)
    const int mt = bid >> 2;       // 0..156
    const int m_base = mt * TM;

    // A staging: 128 rows x 8 k = 256 float4 -> 1 per thread
    const int a_m = tid >> 1;             // 0..127
    const int a_k = (tid & 1) << 2;       // 0 or 4
    const int  row_a = m_base + a_m;
    const bool a_ok  = row_a < N_NODES;
    const float* __restrict__ hrow = h + (size_t)row_a * EMB + a_k;

    // B staging: 8 rows x 256 cols = 512 float4 -> 2 per thread (b_n, b_n+128)
    const int b_k = tid >> 5;             // 0..7
    const int b_n = (tid & 31) << 2;      // 0..124
    const bool isP  = (nt < 2);
    const int w_row_off = isP ? 0 : 128;
    const int cb        = (nt & 1) * TN;  // col base within P/Q (0 or 256)
    const float* __restrict__ wrow = W1 + (size_t)(w_row_off + b_k) * HID + cb + b_n;

    // compute: 16x16 threads; rows {cm..cm+3, cm+64..}, cols {cn, +64, +128, +192}
    const int ty = tid >> 4, tx = tid & 15;
    const int cm = ty << 2, cn = tx << 2;

    v2f acc[8][8] = {};   // [row i][col pair j: groups of 2 within 4 col quads]

    float4 pa, pb0, pb1;
    pa = make_float4(0.f, 0.f, 0.f, 0.f);
    if (a_ok) pa = *(const float4*)(hrow);
    pb0 = *(const float4*)(wrow);
    pb1 = *(const float4*)(wrow + 128);
    As[0][a_k + 0][a_m] = pa.x;
    As[0][a_k + 1][a_m] = pa.y;
    As[0][a_k + 2][a_m] = pa.z;
    As[0][a_k + 3][a_m] = pa.w;
    *(float4*)&Bs[0][b_k][b_n]       = pb0;
    *(float4*)&Bs[0][b_k][b_n + 128] = pb1;
    __syncthreads();

    for (int t = 0; t < NTILES; ++t) {
        const int cur = t & 1;
        if (t + 1 < NTILES) {
            const int k0 = (t + 1) * BK;
            pa = make_float4(0.f, 0.f, 0.f, 0.f);
            if (a_ok) pa = *(const float4*)(hrow + k0);
            pb0 = *(const float4*)(wrow + (size_t)k0 * HID);
            pb1 = *(const float4*)(wrow + (size_t)k0 * HID + 128);
        }

#pragma unroll
        for (int kk = 0; kk < BK; ++kk) {
            float a[8];
            *(float4*)&a[0] = *(const float4*)&As[cur][kk][cm];
            *(float4*)&a[4] = *(const float4*)&As[cur][kk][cm + 64];
            float4 b0 = *(const float4*)&Bs[cur][kk][cn];
            float4 b1v = *(const float4*)&Bs[cur][kk][cn + 64];
            float4 b2v = *(const float4*)&Bs[cur][kk][cn + 128];
            float4 b3v = *(const float4*)&Bs[cur][kk][cn + 192];
            v2f bp[8] = {(v2f){b0.x, b0.y},  (v2f){b0.z, b0.w},
                         (v2f){b1v.x, b1v.y}, (v2f){b1v.z, b1v.w},
                         (v2f){b2v.x, b2v.y}, (v2f){b2v.z, b2v.w},
                         (v2f){b3v.x, b3v.y}, (v2f){b3v.z, b3v.w}};
#pragma unroll
            for (int i = 0; i < 8; ++i) {
                v2f ai = (v2f){a[i], a[i]};
#pragma unroll
                for (int j = 0; j < 8; ++j)
                    acc[i][j] = V2FMA(ai, bp[j], acc[i][j]);
            }
        }

        if (t + 1 < NTILES) {
            const int nxt = 1 - cur;
            As[nxt][a_k + 0][a_m] = pa.x;
            As[nxt][a_k + 1][a_m] = pa.y;
            As[nxt][a_k + 2][a_m] = pa.z;
            As[nxt][a_k + 3][a_m] = pa.w;
            *(float4*)&Bs[nxt][b_k][b_n]       = pb0;
            *(float4*)&Bs[nxt][b_k][b_n + 128] = pb1;
            __syncthreads();
        }
    }

    // epilogue: bias fold for P half only
    v2f bias[8] = {{0.f,0.f},{0.f,0.f},{0.f,0.f},{0.f,0.f},
                   {0.f,0.f},{0.f,0.f},{0.f,0.f},{0.f,0.f}};
    if (isP) {
#pragma unroll
        for (int g = 0; g < 4; ++g) {
            float4 bv = *(const float4*)(b1 + cb + cn + g * 64);
            bias[2*g]   = (v2f){bv.x, bv.y};
            bias[2*g+1] = (v2f){bv.z, bv.w};
        }
    }

    float* __restrict__ dstbase = isP ? P : Q;
#pragma unroll
    for (int i = 0; i < 8; ++i) {
        const int r = m_base + cm + (i < 4 ? i : 64 + i - 4);
        if (r < N_NODES) {
            float* dst = dstbase + (size_t)r * HID + cb;
#pragma unroll
            for (int g = 0; g < 4; ++g) {
                v2f c0 = acc[i][2*g]   + bias[2*g];
                v2f c1 = acc[i][2*g+1] + bias[2*g+1];
                *(float4*)(dst + cn + g * 64) = make_float4(c0.x, c0.y, c1.x, c1.y);
            }
        }
    }
}

// ---------------------------------------------------------------------------
__device__ __forceinline__ int wave_incl_scan(int v, int lane) {
#pragma unroll
    for (int off = 1; off < 64; off <<= 1) {
        int t = __shfl_up(v, off, 64);
        if (lane >= off) v += t;
    }
    return v;
}

__global__ __launch_bounds__(1024) void scan_part(const int* __restrict__ deg,
                                                  int* __restrict__ part,
                                                  int* __restrict__ totals) {
    __shared__ int wsum[16];
    const int tid = threadIdx.x, lane = tid & 63, w = tid >> 6;
    const int i = blockIdx.x * 1024 + tid;
    int v = (i < N_NODES) ? deg[i] : 0;
    int incl = wave_incl_scan(v, lane);
    if (lane == 63) wsum[w] = incl;
    __syncthreads();
    if (w == 0) {
        int x = (lane < 16) ? wsum[lane] : 0;
        int xs = wave_incl_scan(x, lane);
        if (lane < 16) wsum[lane] = xs - x;
        if (lane == 15) totals[blockIdx.x] = xs;
    }
    __syncthreads();
    if (i < N_NODES) part[i] = wsum[w] + incl - v;
}

// scan_carry folded in: every block redundantly scans the 20 chunk totals.
__global__ __launch_bounds__(1024) void scan_apply(const int* __restrict__ part,
                                                   const int* __restrict__ totals,
                                                   int* __restrict__ cursor,
                                                   int* __restrict__ offs) {
    __shared__ int carry_s;
    const int tid = threadIdx.x;
    if (tid < 64) {
        int v = (tid < NCHUNK) ? totals[tid] : 0;
        int incl = wave_incl_scan(v, tid);
        if (tid == (int)blockIdx.x) carry_s = incl - v;   // exclusive carry
    }
    __syncthreads();
    const int i = blockIdx.x * 1024 + tid;
    if (i < N_NODES) {
        int o = part[i] + carry_s;
        cursor[i] = o;
        offs[i] = o;
    }
}

// ---------------------------------------------------------------------------
// scatter: ONE int2 {e, row<<16|col} per edge (lossless: row,col < 32768)
// ---------------------------------------------------------------------------
__global__ void scatter_edges(const int* __restrict__ row, const int* __restrict__ col,
                              int* __restrict__ cursor, int2* __restrict__ rc2) {
    int e = blockIdx.x * 256 + threadIdx.x;
    if (e >= N_EDGES) return;
    int r = row[e];
    int pos = atomicAdd(&cursor[r], 1);
    rc2[pos] = make_int2(e, (r << 16) | col[e]);
}

// ---------------------------------------------------------------------------
// Fused edge phase — champion config (256 thr, RPB=16, x2 unroll; occupancy
// experiments r6/r9 both showed more waves = more thrash = slower).
// ---------------------------------------------------------------------------
__global__ __launch_bounds__(256) void fused_edge(
    const float* __restrict__ P, const float* __restrict__ Q,
    const float* __restrict__ W2, const float* __restrict__ b2,
    const int2* __restrict__ rc2, const int* __restrict__ offs,
    const float* __restrict__ u, const int* __restrict__ edge_mask,
    const int* __restrict__ hierarchy,
    float* __restrict__ scores, float* __restrict__ out_y,
    float* __restrict__ out_mask, float* __restrict__ out_causal,
    float* __restrict__ out_spu)
{
    __shared__ float sc_lds[SC_CAP];

    const int r0 = blockIdx.x * ROWS_PER_BLOCK;
    const int r1 = (r0 + ROWS_PER_BLOCK < N_NODES) ? r0 + ROWS_PER_BLOCK : N_NODES;
    const int e0 = offs[r0];
    const int e1 = offs[r1];
    const int tid = threadIdx.x, lane = tid & 63, w = tid >> 6;
    const int j0 = lane << 2;

    const float4 w0 = *(const float4*)(W2 + j0);
    const float4 w1 = *(const float4*)(W2 + 256 + j0);
    const float bias2 = b2[0];

    // ---- phase 1: scores, two edges per wave-iteration ----
    for (int i0 = e0 + (w << 1); i0 < e1; i0 += 8) {
        const int  iA   = i0;
        const bool hasB = (i0 + 1) < e1;
        const int  iB   = hasB ? i0 + 1 : i0;

        const int2 eA = rc2[iA];
        const int2 eB = rc2[iB];
        const int rA = ((unsigned)eA.y) >> 16, cA = eA.y & 0xFFFF;
        const int rB = ((unsigned)eB.y) >> 16, cB = eB.y & 0xFFFF;
        const float* __restrict__ pA = P + (size_t)rA * HID;
        const float* __restrict__ qA = Q + (size_t)cA * HID;
        const float* __restrict__ pB = P + (size_t)rB * HID;
        const float* __restrict__ qB = Q + (size_t)cB * HID;

        float4 pA0 = *(const float4*)(pA + j0);
        float4 pA1 = *(const float4*)(pA + 256 + j0);
        float4 qA0 = *(const float4*)(qA + j0);
        float4 qA1 = *(const float4*)(qA + 256 + j0);
        float4 pB0 = *(const float4*)(pB + j0);
        float4 pB1 = *(const float4*)(pB + 256 + j0);
        float4 qB0 = *(const float4*)(qB + j0);
        float4 qB1 = *(const float4*)(qB + 256 + j0);

        float sA = 0.0f, sB = 0.0f;
        sA = fmaf(fmaxf(pA0.x + qA0.x, 0.0f), w0.x, sA);
        sA = fmaf(fmaxf(pA0.y + qA0.y, 0.0f), w0.y, sA);
        sA = fmaf(fmaxf(pA0.z + qA0.z, 0.0f), w0.z, sA);
        sA = fmaf(fmaxf(pA0.w + qA0.w, 0.0f), w0.w, sA);
        sA = fmaf(fmaxf(pA1.x + qA1.x, 0.0f), w1.x, sA);
        sA = fmaf(fmaxf(pA1.y + qA1.y, 0.0f), w1.y, sA);
        sA = fmaf(fmaxf(pA1.z + qA1.z, 0.0f), w1.z, sA);
        sA = fmaf(fmaxf(pA1.w + qA1.w, 0.0f), w1.w, sA);
        sB = fmaf(fmaxf(pB0.x + qB0.x, 0.0f), w0.x, sB);
        sB = fmaf(fmaxf(pB0.y + qB0.y, 0.0f), w0.y, sB);
        sB = fmaf(fmaxf(pB0.z + qB0.z, 0.0f), w0.z, sB);
        sB = fmaf(fmaxf(pB0.w + qB0.w, 0.0f), w0.w, sB);
        sB = fmaf(fmaxf(pB1.x + qB1.x, 0.0f), w1.x, sB);
        sB = fmaf(fmaxf(pB1.y + qB1.y, 0.0f), w1.y, sB);
        sB = fmaf(fmaxf(pB1.z + qB1.z, 0.0f), w1.z, sB);
        sB = fmaf(fmaxf(pB1.w + qB1.w, 0.0f), w1.w, sB);

#pragma unroll
        for (int off = 32; off > 0; off >>= 1) {
            sA += __shfl_down(sA, off, 64);
            sB += __shfl_down(sB, off, 64);
        }

        if (lane == 0) {
            float scA = sA + bias2;
            scores[eA.x] = scA;
            int liA = iA - e0;
            if (liA < SC_CAP) sc_lds[liA] = scA;
            if (hasB) {
                float scB = sB + bias2;
                scores[eB.x] = scB;
                int liB = iB - e0;
                if (liB < SC_CAP) sc_lds[liB] = scB;
            }
        }
    }
    __syncthreads();

    // ---- phase 2: wave per row ----
    const int hv = hierarchy[0];
    for (int r = r0 + w; r < r1; r += 4) {
        const int es = offs[r], ee = offs[r + 1];
        const int d = ee - es;
        if (d == 0) continue;

        float m = -INFINITY;
        for (int j = lane; j < d; j += 64) {
            int li = es - e0 + j;
            float s = (li < SC_CAP) ? sc_lds[li] : scores[rc2[es + j].x];
            m = fmaxf(m, s);
        }
#pragma unroll
        for (int off = 32; off > 0; off >>= 1)
            m = fmaxf(m, __shfl_down(m, off, 64));
        m = __shfl(m, 0, 64);

        float ssum = 0.0f;
        for (int j = lane; j < d; j += 64) {
            int li = es - e0 + j;
            float s = (li < SC_CAP) ? sc_lds[li] : scores[rc2[es + j].x];
            ssum += expf(s - m);
        }
#pragma unroll
        for (int off = 32; off > 0; off >>= 1)
            ssum += __shfl_down(ssum, off, 64);
        ssum = __shfl(ssum, 0, 64);

        for (int j = lane; j < d; j += 64) {
            int li = es - e0 + j;
            float s = (li < SC_CAP) ? sc_lds[li] : scores[rc2[es + j].x];
            float p = expf(s - m) / ssum;
            float logits = logf(p) - log1pf(-p);   // +inf when p==1 (d==1)
            int oe = rc2[es + j].x;
            float uu = u[oe];
            float L = logf(uu) - log1pf(-uu);
            float y = 1.0f / (1.0f + expf(-(logits + L)));
            bool hard = y > 0.5f;                  // ST forward value == y_hard
            int mm = hard ? (hv + 1) : edge_mask[oe];
            out_y[oe]      = hard ? 1.0f : 0.0f;
            out_mask[oe]   = (float)mm;
            out_causal[oe] = (mm > 0)   ?  s : 0.0f;
            out_spu[oe]    = (mm == -1) ? -s : 0.0f;
        }
    }
}

// ---------------------------------------------------------------------------
extern "C" void kernel_launch(void* const* d_in, const int* in_sizes, int n_in,
                              void* d_out, int out_size, void* d_ws, size_t ws_size,
                              hipStream_t stream) {
    const float* h_ptr = (const float*)d_in[0];
    const float* W1    = (const float*)d_in[1];
    const float* b1    = (const float*)d_in[2];
    const float* W2    = (const float*)d_in[3];
    const float* b2    = (const float*)d_in[4];
    const float* u     = (const float*)d_in[5];
    const int*   row   = (const int*)d_in[6];
    const int*   col   = (const int*)d_in[7];
    const int*   emask = (const int*)d_in[8];
    const int*   hier  = (const int*)d_in[9];

    float* out        = (float*)d_out;
    float* scores     = out;                        // [E]
    float* out_y      = out + (size_t)N_EDGES;      // [E]
    float* out_mask   = out + 2 * (size_t)N_EDGES;  // [E]
    float* out_causal = out + 3 * (size_t)N_EDGES;  // [E]
    float* out_spu    = out + 4 * (size_t)N_EDGES;  // [E]

    // workspace (4B units): P, Q first (16B align), rc2 (8B align), then ints
    float* P      = (float*)d_ws;
    float* Qm     = P + (size_t)N_NODES * HID;
    int2*  rc2    = (int2*)(Qm + (size_t)N_NODES * HID);   // [E] int2
    int*   deg    = (int*)(rc2 + N_EDGES);
    int*   cursor = deg + N_NODES;
    int*   offs   = cursor + N_NODES;               // [N_NODES+1]
    int*   part   = offs + N_NODES + 1;
    int*   totals = part + N_NODES;                 // [NCHUNK]

    hipLaunchKernelGGL(init_deg, dim3((N_NODES + 255) / 256), dim3(256), 0, stream,
                       deg, offs);

    hipLaunchKernelGGL(gemm_hist, dim3(GEMM_BLOCKS + HIST_BLOCKS), dim3(256), 0, stream,
                       h_ptr, W1, b1, P, Qm, row, deg);

    hipLaunchKernelGGL(scan_part, dim3(NCHUNK), dim3(1024), 0, stream, deg, part, totals);
    hipLaunchKernelGGL(scan_apply, dim3(NCHUNK), dim3(1024), 0, stream,
                       part, totals, cursor, offs);
    hipLaunchKernelGGL(scatter_edges, dim3((N_EDGES + 255) / 256), dim3(256), 0, stream,
                       row, col, cursor, rc2);

    hipLaunchKernelGGL(fused_edge, dim3((N_NODES + ROWS_PER_BLOCK - 1) / ROWS_PER_BLOCK),
                       dim3(256), 0, stream,
                       P, Qm, W2, b2, rc2, offs, u, emask, hier,
                       scores, out_y, out_mask, out_causal, out_spu);
}

// Round 13
// 298.835 us; speedup vs baseline: 1.8136x; 1.1113x over previous
//
#include <hip/hip_runtime.h>
#include <math.h>

#define N_NODES 20000
#define N_EDGES 320000
#define EMB 128
#define HID 512          // 4*EMB
#define ROWS_PER_BLOCK 16
#define SC_CAP 2048      // LDS score cache per block
#define NCHUNK ((N_NODES + 1023) / 1024)   // 20

typedef float v2f __attribute__((ext_vector_type(2)));

#if defined(__has_builtin)
#if __has_builtin(__builtin_elementwise_fma)
#define V2FMA(a, b, c) __builtin_elementwise_fma((a), (b), (c))
#else
#define V2FMA(a, b, c) ((a) * (b) + (c))
#endif
#else
#define V2FMA(a, b, c) ((a) * (b) + (c))
#endif

// ---------------------------------------------------------------------------
// K1: heterogeneous blocks — [0,GEMM_BLOCKS) = GEMM, rest = row histogram.
// GEMM config = round-10 champion: 128x128 tile, BK=8, 256 thr, 8x8 micro,
// LDS double-buffer (16.6 KB, ~5 blocks/CU). r11 (no-LDS) and r12 (8x16
// micro) both regressed — this shape is the measured optimum.
// deg is zeroed by hipMemsetAsync before this kernel.
// ---------------------------------------------------------------------------
#define TM 128
#define TN 128
#define BK 8
#define NTILES (EMB / BK)                    // 16
#define GEMM_MT ((N_NODES + TM - 1) / TM)    // 157
#define GEMM_BLOCKS (8 * GEMM_MT)            // 1256
#define HIST_BLOCKS ((N_EDGES + 255) / 256)  // 1250

__global__ __launch_bounds__(256) void gemm_hist(
    const float* __restrict__ h, const float* __restrict__ W1,
    const float* __restrict__ b1, float* __restrict__ P, float* __restrict__ Q,
    const int* __restrict__ row, int* __restrict__ deg)
{
    const int bid = blockIdx.x;
    const int tid = threadIdx.x;

    if (bid >= GEMM_BLOCKS) {
        // ---- histogram path ----
        const int e = (bid - GEMM_BLOCKS) * 256 + tid;
        if (e < N_EDGES) atomicAdd(&deg[row[e]], 1);
        return;
    }

    // ---- gemm path ----
    __shared__ float As[2][BK][TM + 4];   // transposed A, stride 132
    __shared__ float Bs[2][BK][TN];

    const int nt = bid & 7;        // 0..7 (1256 = 8*157 exactly)
    const int mt = bid >> 3;       // 0..156
    const int m_base = mt * TM;

    // A staging: 128 rows x 8 k = 256 float4 -> 1 per thread
    const int a_m = tid >> 1;             // 0..127
    const int a_k = (tid & 1) << 2;       // 0 or 4
    const int  row_a = m_base + a_m;
    const bool a_ok  = row_a < N_NODES;
    const float* __restrict__ hrow = h + (size_t)row_a * EMB + a_k;

    // B staging: 8 rows x 128 cols = 256 float4 -> 1 per thread
    const int b_k = tid >> 5;             // 0..7
    const int b_n = (tid & 31) << 2;      // 0..124
    const bool isP = (nt < 4);
    const int w_row_off = isP ? 0 : 128;
    const int cb        = (nt & 3) * TN;  // col base within P/Q
    const float* __restrict__ wrow = W1 + (size_t)(w_row_off + b_k) * HID + cb + b_n;

    // compute: 16x16 threads, rows {cm..cm+3, cm+64..cm+67}, cols likewise
    const int ty = tid >> 4, tx = tid & 15;
    const int cm = ty << 2, cn = tx << 2;

    v2f acc[8][4] = {};

    float4 pa, pb;
    pa = make_float4(0.f, 0.f, 0.f, 0.f);
    if (a_ok) pa = *(const float4*)(hrow);
    pb = *(const float4*)(wrow);
    As[0][a_k + 0][a_m] = pa.x;
    As[0][a_k + 1][a_m] = pa.y;
    As[0][a_k + 2][a_m] = pa.z;
    As[0][a_k + 3][a_m] = pa.w;
    *(float4*)&Bs[0][b_k][b_n] = pb;
    __syncthreads();

    for (int t = 0; t < NTILES; ++t) {
        const int cur = t & 1;
        if (t + 1 < NTILES) {
            const int k0 = (t + 1) * BK;
            pa = make_float4(0.f, 0.f, 0.f, 0.f);
            if (a_ok) pa = *(const float4*)(hrow + k0);
            pb = *(const float4*)(wrow + (size_t)k0 * HID);
        }

#pragma unroll
        for (int kk = 0; kk < BK; ++kk) {
            float a[8];
            *(float4*)&a[0] = *(const float4*)&As[cur][kk][cm];
            *(float4*)&a[4] = *(const float4*)&As[cur][kk][cm + 64];
            float4 b0 = *(const float4*)&Bs[cur][kk][cn];
            float4 b1v = *(const float4*)&Bs[cur][kk][cn + 64];
            v2f bp[4] = {(v2f){b0.x, b0.y}, (v2f){b0.z, b0.w},
                         (v2f){b1v.x, b1v.y}, (v2f){b1v.z, b1v.w}};
#pragma unroll
            for (int i = 0; i < 8; ++i) {
                v2f ai = (v2f){a[i], a[i]};
#pragma unroll
                for (int j = 0; j < 4; ++j)
                    acc[i][j] = V2FMA(ai, bp[j], acc[i][j]);
            }
        }

        if (t + 1 < NTILES) {
            const int nxt = 1 - cur;
            As[nxt][a_k + 0][a_m] = pa.x;
            As[nxt][a_k + 1][a_m] = pa.y;
            As[nxt][a_k + 2][a_m] = pa.z;
            As[nxt][a_k + 3][a_m] = pa.w;
            *(float4*)&Bs[nxt][b_k][b_n] = pb;
            __syncthreads();
        }
    }

    v2f bias[4] = {{0.f,0.f},{0.f,0.f},{0.f,0.f},{0.f,0.f}};
    if (isP) {  // bias fold: P half only
        float4 bv0 = *(const float4*)(b1 + cb + cn);
        float4 bv1 = *(const float4*)(b1 + cb + cn + 64);
        bias[0] = (v2f){bv0.x, bv0.y};
        bias[1] = (v2f){bv0.z, bv0.w};
        bias[2] = (v2f){bv1.x, bv1.y};
        bias[3] = (v2f){bv1.z, bv1.w};
    }

    float* __restrict__ dstbase = isP ? P : Q;
#pragma unroll
    for (int i = 0; i < 8; ++i) {
        const int r = m_base + cm + (i < 4 ? i : 64 + i - 4);
        if (r < N_NODES) {
            float* dst = dstbase + (size_t)r * HID + cb;
            v2f c0 = acc[i][0] + bias[0], c1 = acc[i][1] + bias[1];
            v2f c2 = acc[i][2] + bias[2], c3 = acc[i][3] + bias[3];
            *(float4*)(dst + cn)      = make_float4(c0.x, c0.y, c1.x, c1.y);
            *(float4*)(dst + cn + 64) = make_float4(c2.x, c2.y, c3.x, c3.y);
        }
    }
}

// ---------------------------------------------------------------------------
__device__ __forceinline__ int wave_incl_scan(int v, int lane) {
#pragma unroll
    for (int off = 1; off < 64; off <<= 1) {
        int t = __shfl_up(v, off, 64);
        if (lane >= off) v += t;
    }
    return v;
}

__global__ __launch_bounds__(1024) void scan_part(const int* __restrict__ deg,
                                                  int* __restrict__ part,
                                                  int* __restrict__ totals) {
    __shared__ int wsum[16];
    const int tid = threadIdx.x, lane = tid & 63, w = tid >> 6;
    const int i = blockIdx.x * 1024 + tid;
    int v = (i < N_NODES) ? deg[i] : 0;
    int incl = wave_incl_scan(v, lane);
    if (lane == 63) wsum[w] = incl;
    __syncthreads();
    if (w == 0) {
        int x = (lane < 16) ? wsum[lane] : 0;
        int xs = wave_incl_scan(x, lane);
        if (lane < 16) wsum[lane] = xs - x;
        if (lane == 15) totals[blockIdx.x] = xs;
    }
    __syncthreads();
    if (i < N_NODES) part[i] = wsum[w] + incl - v;
}

// scan_carry folded in (redundant per-block scan of 20 totals); also writes
// the offs[N_NODES] sentinel (previously done by the init kernel).
__global__ __launch_bounds__(1024) void scan_apply(const int* __restrict__ part,
                                                   const int* __restrict__ totals,
                                                   int* __restrict__ cursor,
                                                   int* __restrict__ offs) {
    __shared__ int carry_s;
    const int tid = threadIdx.x;
    if (tid < 64) {
        int v = (tid < NCHUNK) ? totals[tid] : 0;
        int incl = wave_incl_scan(v, tid);
        if (tid == (int)blockIdx.x) carry_s = incl - v;   // exclusive carry
    }
    if (blockIdx.x == 0 && tid == 0) offs[N_NODES] = N_EDGES;
    __syncthreads();
    const int i = blockIdx.x * 1024 + tid;
    if (i < N_NODES) {
        int o = part[i] + carry_s;
        cursor[i] = o;
        offs[i] = o;
    }
}

// ---------------------------------------------------------------------------
// scatter: ONE int2 {e, row<<16|col} per edge (lossless: row,col < 32768)
// ---------------------------------------------------------------------------
__global__ void scatter_edges(const int* __restrict__ row, const int* __restrict__ col,
                              int* __restrict__ cursor, int2* __restrict__ rc2) {
    int e = blockIdx.x * 256 + threadIdx.x;
    if (e >= N_EDGES) return;
    int r = row[e];
    int pos = atomicAdd(&cursor[r], 1);
    rc2[pos] = make_int2(e, (r << 16) | col[e]);
}

// ---------------------------------------------------------------------------
// Fused edge phase — champion config (256 thr, RPB=16, x2 unroll; r6/r9
// occupancy probes: more waves = cache thrash = slower). Output stores are
// NONTEMPORAL (write-only scattered 4B stores; avoid read-for-ownership
// line fills).
// ---------------------------------------------------------------------------
__global__ __launch_bounds__(256) void fused_edge(
    const float* __restrict__ P, const float* __restrict__ Q,
    const float* __restrict__ W2, const float* __restrict__ b2,
    const int2* __restrict__ rc2, const int* __restrict__ offs,
    const float* __restrict__ u, const int* __restrict__ edge_mask,
    const int* __restrict__ hierarchy,
    float* __restrict__ scores, float* __restrict__ out_y,
    float* __restrict__ out_mask, float* __restrict__ out_causal,
    float* __restrict__ out_spu)
{
    __shared__ float sc_lds[SC_CAP];

    const int r0 = blockIdx.x * ROWS_PER_BLOCK;
    const int r1 = (r0 + ROWS_PER_BLOCK < N_NODES) ? r0 + ROWS_PER_BLOCK : N_NODES;
    const int e0 = offs[r0];
    const int e1 = offs[r1];
    const int tid = threadIdx.x, lane = tid & 63, w = tid >> 6;
    const int j0 = lane << 2;

    const float4 w0 = *(const float4*)(W2 + j0);
    const float4 w1 = *(const float4*)(W2 + 256 + j0);
    const float bias2 = b2[0];

    // ---- phase 1: scores, two edges per wave-iteration ----
    for (int i0 = e0 + (w << 1); i0 < e1; i0 += 8) {
        const int  iA   = i0;
        const bool hasB = (i0 + 1) < e1;
        const int  iB   = hasB ? i0 + 1 : i0;

        const int2 eA = rc2[iA];
        const int2 eB = rc2[iB];
        const int rA = ((unsigned)eA.y) >> 16, cA = eA.y & 0xFFFF;
        const int rB = ((unsigned)eB.y) >> 16, cB = eB.y & 0xFFFF;
        const float* __restrict__ pA = P + (size_t)rA * HID;
        const float* __restrict__ qA = Q + (size_t)cA * HID;
        const float* __restrict__ pB = P + (size_t)rB * HID;
        const float* __restrict__ qB = Q + (size_t)cB * HID;

        float4 pA0 = *(const float4*)(pA + j0);
        float4 pA1 = *(const float4*)(pA + 256 + j0);
        float4 qA0 = *(const float4*)(qA + j0);
        float4 qA1 = *(const float4*)(qA + 256 + j0);
        float4 pB0 = *(const float4*)(pB + j0);
        float4 pB1 = *(const float4*)(pB + 256 + j0);
        float4 qB0 = *(const float4*)(qB + j0);
        float4 qB1 = *(const float4*)(qB + 256 + j0);

        float sA = 0.0f, sB = 0.0f;
        sA = fmaf(fmaxf(pA0.x + qA0.x, 0.0f), w0.x, sA);
        sA = fmaf(fmaxf(pA0.y + qA0.y, 0.0f), w0.y, sA);
        sA = fmaf(fmaxf(pA0.z + qA0.z, 0.0f), w0.z, sA);
        sA = fmaf(fmaxf(pA0.w + qA0.w, 0.0f), w0.w, sA);
        sA = fmaf(fmaxf(pA1.x + qA1.x, 0.0f), w1.x, sA);
        sA = fmaf(fmaxf(pA1.y + qA1.y, 0.0f), w1.y, sA);
        sA = fmaf(fmaxf(pA1.z + qA1.z, 0.0f), w1.z, sA);
        sA = fmaf(fmaxf(pA1.w + qA1.w, 0.0f), w1.w, sA);
        sB = fmaf(fmaxf(pB0.x + qB0.x, 0.0f), w0.x, sB);
        sB = fmaf(fmaxf(pB0.y + qB0.y, 0.0f), w0.y, sB);
        sB = fmaf(fmaxf(pB0.z + qB0.z, 0.0f), w0.z, sB);
        sB = fmaf(fmaxf(pB0.w + qB0.w, 0.0f), w0.w, sB);
        sB = fmaf(fmaxf(pB1.x + qB1.x, 0.0f), w1.x, sB);
        sB = fmaf(fmaxf(pB1.y + qB1.y, 0.0f), w1.y, sB);
        sB = fmaf(fmaxf(pB1.z + qB1.z, 0.0f), w1.z, sB);
        sB = fmaf(fmaxf(pB1.w + qB1.w, 0.0f), w1.w, sB);

#pragma unroll
        for (int off = 32; off > 0; off >>= 1) {
            sA += __shfl_down(sA, off, 64);
            sB += __shfl_down(sB, off, 64);
        }

        if (lane == 0) {
            float scA = sA + bias2;
            __builtin_nontemporal_store(scA, &scores[eA.x]);
            int liA = iA - e0;
            if (liA < SC_CAP) sc_lds[liA] = scA;
            if (hasB) {
                float scB = sB + bias2;
                __builtin_nontemporal_store(scB, &scores[eB.x]);
                int liB = iB - e0;
                if (liB < SC_CAP) sc_lds[liB] = scB;
            }
        }
    }
    __syncthreads();

    // ---- phase 2: wave per row ----
    const int hv = hierarchy[0];
    for (int r = r0 + w; r < r1; r += 4) {
        const int es = offs[r], ee = offs[r + 1];
        const int d = ee - es;
        if (d == 0) continue;

        float m = -INFINITY;
        for (int j = lane; j < d; j += 64) {
            int li = es - e0 + j;
            float s = (li < SC_CAP) ? sc_lds[li] : scores[rc2[es + j].x];
            m = fmaxf(m, s);
        }
#pragma unroll
        for (int off = 32; off > 0; off >>= 1)
            m = fmaxf(m, __shfl_down(m, off, 64));
        m = __shfl(m, 0, 64);

        float ssum = 0.0f;
        for (int j = lane; j < d; j += 64) {
            int li = es - e0 + j;
            float s = (li < SC_CAP) ? sc_lds[li] : scores[rc2[es + j].x];
            ssum += expf(s - m);
        }
#pragma unroll
        for (int off = 32; off > 0; off >>= 1)
            ssum += __shfl_down(ssum, off, 64);
        ssum = __shfl(ssum, 0, 64);

        for (int j = lane; j < d; j += 64) {
            int li = es - e0 + j;
            float s = (li < SC_CAP) ? sc_lds[li] : scores[rc2[es + j].x];
            float p = expf(s - m) / ssum;
            float logits = logf(p) - log1pf(-p);   // +inf when p==1 (d==1)
            int oe = rc2[es + j].x;
            float uu = u[oe];
            float L = logf(uu) - log1pf(-uu);
            float y = 1.0f / (1.0f + expf(-(logits + L)));
            bool hard = y > 0.5f;                  // ST forward value == y_hard
            int mm = hard ? (hv + 1) : edge_mask[oe];
            __builtin_nontemporal_store(hard ? 1.0f : 0.0f, &out_y[oe]);
            __builtin_nontemporal_store((float)mm,          &out_mask[oe]);
            __builtin_nontemporal_store((mm > 0)   ?  s : 0.0f, &out_causal[oe]);
            __builtin_nontemporal_store((mm == -1) ? -s : 0.0f, &out_spu[oe]);
        }
    }
}

// ---------------------------------------------------------------------------
extern "C" void kernel_launch(void* const* d_in, const int* in_sizes, int n_in,
                              void* d_out, int out_size, void* d_ws, size_t ws_size,
                              hipStream_t stream) {
    const float* h_ptr = (const float*)d_in[0];
    const float* W1    = (const float*)d_in[1];
    const float* b1    = (const float*)d_in[2];
    const float* W2    = (const float*)d_in[3];
    const float* b2    = (const float*)d_in[4];
    const float* u     = (const float*)d_in[5];
    const int*   row   = (const int*)d_in[6];
    const int*   col   = (const int*)d_in[7];
    const int*   emask = (const int*)d_in[8];
    const int*   hier  = (const int*)d_in[9];

    float* out        = (float*)d_out;
    float* scores     = out;                        // [E]
    float* out_y      = out + (size_t)N_EDGES;      // [E]
    float* out_mask   = out + 2 * (size_t)N_EDGES;  // [E]
    float* out_causal = out + 3 * (size_t)N_EDGES;  // [E]
    float* out_spu    = out + 4 * (size_t)N_EDGES;  // [E]

    // workspace (4B units): P, Q first (16B align), rc2 (8B align), then ints
    float* P      = (float*)d_ws;
    float* Qm     = P + (size_t)N_NODES * HID;
    int2*  rc2    = (int2*)(Qm + (size_t)N_NODES * HID);   // [E] int2
    int*   deg    = (int*)(rc2 + N_EDGES);
    int*   cursor = deg + N_NODES;
    int*   offs   = cursor + N_NODES;               // [N_NODES+1]
    int*   part   = offs + N_NODES + 1;
    int*   totals = part + N_NODES;                 // [NCHUNK]

    // init: zero deg via async memset (capture-safe); offs sentinel moved
    // into scan_apply. One fewer kernel dispatch.
    hipMemsetAsync(deg, 0, (size_t)N_NODES * sizeof(int), stream);

    hipLaunchKernelGGL(gemm_hist, dim3(GEMM_BLOCKS + HIST_BLOCKS), dim3(256), 0, stream,
                       h_ptr, W1, b1, P, Qm, row, deg);

    hipLaunchKernelGGL(scan_part, dim3(NCHUNK), dim3(1024), 0, stream, deg, part, totals);
    hipLaunchKernelGGL(scan_apply, dim3(NCHUNK), dim3(1024), 0, stream,
                       part, totals, cursor, offs);
    hipLaunchKernelGGL(scatter_edges, dim3((N_EDGES + 255) / 256), dim3(256), 0, stream,
                       row, col, cursor, rc2);

    hipLaunchKernelGGL(fused_edge, dim3((N_NODES + ROWS_PER_BLOCK - 1) / ROWS_PER_BLOCK),
                       dim3(256), 0, stream,
                       P, Qm, W2, b2, rc2, offs, u, emask, hier,
                       scores, out_y, out_mask, out_causal, out_spu);
}

// Round 14
// 288.290 us; speedup vs baseline: 1.8800x; 1.0366x over previous
//
#include <hip/hip_runtime.h>
#include <math.h>

#define N_NODES 20000
#define N_EDGES 320000
#define EMB 128
#define HID 512          // 4*EMB
#define ROWS_PER_BLOCK 16
#define SC_CAP 2048      // LDS score cache per block
#define NCHUNK ((N_NODES + 1023) / 1024)   // 20

typedef float v2f __attribute__((ext_vector_type(2)));

#if defined(__has_builtin)
#if __has_builtin(__builtin_elementwise_fma)
#define V2FMA(a, b, c) __builtin_elementwise_fma((a), (b), (c))
#else
#define V2FMA(a, b, c) ((a) * (b) + (c))
#endif
#else
#define V2FMA(a, b, c) ((a) * (b) + (c))
#endif

// ---------------------------------------------------------------------------
// K1: heterogeneous blocks — [0,GEMM_BLOCKS) = GEMM, rest = row histogram.
// GEMM config = round-10 champion: 128x128 tile, BK=8, 256 thr, 8x8 micro,
// LDS double-buffer. (r11 no-LDS and r12 8x16-micro both regressed.)
// deg is zeroed by hipMemsetAsync before this kernel.
// ---------------------------------------------------------------------------
#define TM 128
#define TN 128
#define BK 8
#define NTILES (EMB / BK)                    // 16
#define GEMM_MT ((N_NODES + TM - 1) / TM)    // 157
#define GEMM_BLOCKS (8 * GEMM_MT)            // 1256
#define HIST_BLOCKS ((N_EDGES + 255) / 256)  // 1250

__global__ __launch_bounds__(256) void gemm_hist(
    const float* __restrict__ h, const float* __restrict__ W1,
    const float* __restrict__ b1, float* __restrict__ P, float* __restrict__ Q,
    const int* __restrict__ row, int* __restrict__ deg)
{
    const int bid = blockIdx.x;
    const int tid = threadIdx.x;

    if (bid >= GEMM_BLOCKS) {
        // ---- histogram path ----
        const int e = (bid - GEMM_BLOCKS) * 256 + tid;
        if (e < N_EDGES) atomicAdd(&deg[row[e]], 1);
        return;
    }

    // ---- gemm path ----
    __shared__ float As[2][BK][TM + 4];   // transposed A, stride 132
    __shared__ float Bs[2][BK][TN];

    const int nt = bid & 7;        // 0..7 (1256 = 8*157 exactly)
    const int mt = bid >> 3;       // 0..156
    const int m_base = mt * TM;

    // A staging: 128 rows x 8 k = 256 float4 -> 1 per thread
    const int a_m = tid >> 1;             // 0..127
    const int a_k = (tid & 1) << 2;       // 0 or 4
    const int  row_a = m_base + a_m;
    const bool a_ok  = row_a < N_NODES;
    const float* __restrict__ hrow = h + (size_t)row_a * EMB + a_k;

    // B staging: 8 rows x 128 cols = 256 float4 -> 1 per thread
    const int b_k = tid >> 5;             // 0..7
    const int b_n = (tid & 31) << 2;      // 0..124
    const bool isP = (nt < 4);
    const int w_row_off = isP ? 0 : 128;
    const int cb        = (nt & 3) * TN;  // col base within P/Q
    const float* __restrict__ wrow = W1 + (size_t)(w_row_off + b_k) * HID + cb + b_n;

    // compute: 16x16 threads, rows {cm..cm+3, cm+64..cm+67}, cols likewise
    const int ty = tid >> 4, tx = tid & 15;
    const int cm = ty << 2, cn = tx << 2;

    v2f acc[8][4] = {};

    float4 pa, pb;
    pa = make_float4(0.f, 0.f, 0.f, 0.f);
    if (a_ok) pa = *(const float4*)(hrow);
    pb = *(const float4*)(wrow);
    As[0][a_k + 0][a_m] = pa.x;
    As[0][a_k + 1][a_m] = pa.y;
    As[0][a_k + 2][a_m] = pa.z;
    As[0][a_k + 3][a_m] = pa.w;
    *(float4*)&Bs[0][b_k][b_n] = pb;
    __syncthreads();

    for (int t = 0; t < NTILES; ++t) {
        const int cur = t & 1;
        if (t + 1 < NTILES) {
            const int k0 = (t + 1) * BK;
            pa = make_float4(0.f, 0.f, 0.f, 0.f);
            if (a_ok) pa = *(const float4*)(hrow + k0);
            pb = *(const float4*)(wrow + (size_t)k0 * HID);
        }

#pragma unroll
        for (int kk = 0; kk < BK; ++kk) {
            float a[8];
            *(float4*)&a[0] = *(const float4*)&As[cur][kk][cm];
            *(float4*)&a[4] = *(const float4*)&As[cur][kk][cm + 64];
            float4 b0 = *(const float4*)&Bs[cur][kk][cn];
            float4 b1v = *(const float4*)&Bs[cur][kk][cn + 64];
            v2f bp[4] = {(v2f){b0.x, b0.y}, (v2f){b0.z, b0.w},
                         (v2f){b1v.x, b1v.y}, (v2f){b1v.z, b1v.w}};
#pragma unroll
            for (int i = 0; i < 8; ++i) {
                v2f ai = (v2f){a[i], a[i]};
#pragma unroll
                for (int j = 0; j < 4; ++j)
                    acc[i][j] = V2FMA(ai, bp[j], acc[i][j]);
            }
        }

        if (t + 1 < NTILES) {
            const int nxt = 1 - cur;
            As[nxt][a_k + 0][a_m] = pa.x;
            As[nxt][a_k + 1][a_m] = pa.y;
            As[nxt][a_k + 2][a_m] = pa.z;
            As[nxt][a_k + 3][a_m] = pa.w;
            *(float4*)&Bs[nxt][b_k][b_n] = pb;
            __syncthreads();
        }
    }

    v2f bias[4] = {{0.f,0.f},{0.f,0.f},{0.f,0.f},{0.f,0.f}};
    if (isP) {  // bias fold: P half only
        float4 bv0 = *(const float4*)(b1 + cb + cn);
        float4 bv1 = *(const float4*)(b1 + cb + cn + 64);
        bias[0] = (v2f){bv0.x, bv0.y};
        bias[1] = (v2f){bv0.z, bv0.w};
        bias[2] = (v2f){bv1.x, bv1.y};
        bias[3] = (v2f){bv1.z, bv1.w};
    }

    float* __restrict__ dstbase = isP ? P : Q;
#pragma unroll
    for (int i = 0; i < 8; ++i) {
        const int r = m_base + cm + (i < 4 ? i : 64 + i - 4);
        if (r < N_NODES) {
            float* dst = dstbase + (size_t)r * HID + cb;
            v2f c0 = acc[i][0] + bias[0], c1 = acc[i][1] + bias[1];
            v2f c2 = acc[i][2] + bias[2], c3 = acc[i][3] + bias[3];
            *(float4*)(dst + cn)      = make_float4(c0.x, c0.y, c1.x, c1.y);
            *(float4*)(dst + cn + 64) = make_float4(c2.x, c2.y, c3.x, c3.y);
        }
    }
}

// ---------------------------------------------------------------------------
__device__ __forceinline__ int wave_incl_scan(int v, int lane) {
#pragma unroll
    for (int off = 1; off < 64; off <<= 1) {
        int t = __shfl_up(v, off, 64);
        if (lane >= off) v += t;
    }
    return v;
}

__global__ __launch_bounds__(1024) void scan_part(const int* __restrict__ deg,
                                                  int* __restrict__ part,
                                                  int* __restrict__ totals) {
    __shared__ int wsum[16];
    const int tid = threadIdx.x, lane = tid & 63, w = tid >> 6;
    const int i = blockIdx.x * 1024 + tid;
    int v = (i < N_NODES) ? deg[i] : 0;
    int incl = wave_incl_scan(v, lane);
    if (lane == 63) wsum[w] = incl;
    __syncthreads();
    if (w == 0) {
        int x = (lane < 16) ? wsum[lane] : 0;
        int xs = wave_incl_scan(x, lane);
        if (lane < 16) wsum[lane] = xs - x;
        if (lane == 15) totals[blockIdx.x] = xs;
    }
    __syncthreads();
    if (i < N_NODES) part[i] = wsum[w] + incl - v;
}

// scan_carry folded in (redundant per-block scan of 20 totals); also writes
// the offs[N_NODES] sentinel.
__global__ __launch_bounds__(1024) void scan_apply(const int* __restrict__ part,
                                                   const int* __restrict__ totals,
                                                   int* __restrict__ cursor,
                                                   int* __restrict__ offs) {
    __shared__ int carry_s;
    const int tid = threadIdx.x;
    if (tid < 64) {
        int v = (tid < NCHUNK) ? totals[tid] : 0;
        int incl = wave_incl_scan(v, tid);
        if (tid == (int)blockIdx.x) carry_s = incl - v;   // exclusive carry
    }
    if (blockIdx.x == 0 && tid == 0) offs[N_NODES] = N_EDGES;
    __syncthreads();
    const int i = blockIdx.x * 1024 + tid;
    if (i < N_NODES) {
        int o = part[i] + carry_s;
        cursor[i] = o;
        offs[i] = o;
    }
}

// ---------------------------------------------------------------------------
// scatter: ONE int2 {e, row<<16|col} per edge (lossless: row,col < 32768)
// ---------------------------------------------------------------------------
__global__ void scatter_edges(const int* __restrict__ row, const int* __restrict__ col,
                              int* __restrict__ cursor, int2* __restrict__ rc2) {
    int e = blockIdx.x * 256 + threadIdx.x;
    if (e >= N_EDGES) return;
    int r = row[e];
    int pos = atomicAdd(&cursor[r], 1);
    rc2[pos] = make_int2(e, (r << 16) | col[e]);
}

// ---------------------------------------------------------------------------
// Fused edge phase — champion config (256 thr, RPB=16, x2 unroll, PLAIN
// stores: r13's nontemporal stores regressed 117->129 — NT bypasses L2
// write-combining and starves the store path for scattered 4B stores).
// ---------------------------------------------------------------------------
__global__ __launch_bounds__(256) void fused_edge(
    const float* __restrict__ P, const float* __restrict__ Q,
    const float* __restrict__ W2, const float* __restrict__ b2,
    const int2* __restrict__ rc2, const int* __restrict__ offs,
    const float* __restrict__ u, const int* __restrict__ edge_mask,
    const int* __restrict__ hierarchy,
    float* __restrict__ scores, float* __restrict__ out_y,
    float* __restrict__ out_mask, float* __restrict__ out_causal,
    float* __restrict__ out_spu)
{
    __shared__ float sc_lds[SC_CAP];

    const int r0 = blockIdx.x * ROWS_PER_BLOCK;
    const int r1 = (r0 + ROWS_PER_BLOCK < N_NODES) ? r0 + ROWS_PER_BLOCK : N_NODES;
    const int e0 = offs[r0];
    const int e1 = offs[r1];
    const int tid = threadIdx.x, lane = tid & 63, w = tid >> 6;
    const int j0 = lane << 2;

    const float4 w0 = *(const float4*)(W2 + j0);
    const float4 w1 = *(const float4*)(W2 + 256 + j0);
    const float bias2 = b2[0];

    // ---- phase 1: scores, two edges per wave-iteration ----
    for (int i0 = e0 + (w << 1); i0 < e1; i0 += 8) {
        const int  iA   = i0;
        const bool hasB = (i0 + 1) < e1;
        const int  iB   = hasB ? i0 + 1 : i0;

        const int2 eA = rc2[iA];
        const int2 eB = rc2[iB];
        const int rA = ((unsigned)eA.y) >> 16, cA = eA.y & 0xFFFF;
        const int rB = ((unsigned)eB.y) >> 16, cB = eB.y & 0xFFFF;
        const float* __restrict__ pA = P + (size_t)rA * HID;
        const float* __restrict__ qA = Q + (size_t)cA * HID;
        const float* __restrict__ pB = P + (size_t)rB * HID;
        const float* __restrict__ qB = Q + (size_t)cB * HID;

        float4 pA0 = *(const float4*)(pA + j0);
        float4 pA1 = *(const float4*)(pA + 256 + j0);
        float4 qA0 = *(const float4*)(qA + j0);
        float4 qA1 = *(const float4*)(qA + 256 + j0);
        float4 pB0 = *(const float4*)(pB + j0);
        float4 pB1 = *(const float4*)(pB + 256 + j0);
        float4 qB0 = *(const float4*)(qB + j0);
        float4 qB1 = *(const float4*)(qB + 256 + j0);

        float sA = 0.0f, sB = 0.0f;
        sA = fmaf(fmaxf(pA0.x + qA0.x, 0.0f), w0.x, sA);
        sA = fmaf(fmaxf(pA0.y + qA0.y, 0.0f), w0.y, sA);
        sA = fmaf(fmaxf(pA0.z + qA0.z, 0.0f), w0.z, sA);
        sA = fmaf(fmaxf(pA0.w + qA0.w, 0.0f), w0.w, sA);
        sA = fmaf(fmaxf(pA1.x + qA1.x, 0.0f), w1.x, sA);
        sA = fmaf(fmaxf(pA1.y + qA1.y, 0.0f), w1.y, sA);
        sA = fmaf(fmaxf(pA1.z + qA1.z, 0.0f), w1.z, sA);
        sA = fmaf(fmaxf(pA1.w + qA1.w, 0.0f), w1.w, sA);
        sB = fmaf(fmaxf(pB0.x + qB0.x, 0.0f), w0.x, sB);
        sB = fmaf(fmaxf(pB0.y + qB0.y, 0.0f), w0.y, sB);
        sB = fmaf(fmaxf(pB0.z + qB0.z, 0.0f), w0.z, sB);
        sB = fmaf(fmaxf(pB0.w + qB0.w, 0.0f), w0.w, sB);
        sB = fmaf(fmaxf(pB1.x + qB1.x, 0.0f), w1.x, sB);
        sB = fmaf(fmaxf(pB1.y + qB1.y, 0.0f), w1.y, sB);
        sB = fmaf(fmaxf(pB1.z + qB1.z, 0.0f), w1.z, sB);
        sB = fmaf(fmaxf(pB1.w + qB1.w, 0.0f), w1.w, sB);

#pragma unroll
        for (int off = 32; off > 0; off >>= 1) {
            sA += __shfl_down(sA, off, 64);
            sB += __shfl_down(sB, off, 64);
        }

        if (lane == 0) {
            float scA = sA + bias2;
            scores[eA.x] = scA;
            int liA = iA - e0;
            if (liA < SC_CAP) sc_lds[liA] = scA;
            if (hasB) {
                float scB = sB + bias2;
                scores[eB.x] = scB;
                int liB = iB - e0;
                if (liB < SC_CAP) sc_lds[liB] = scB;
            }
        }
    }
    __syncthreads();

    // ---- phase 2: wave per row ----
    const int hv = hierarchy[0];
    for (int r = r0 + w; r < r1; r += 4) {
        const int es = offs[r], ee = offs[r + 1];
        const int d = ee - es;
        if (d == 0) continue;

        float m = -INFINITY;
        for (int j = lane; j < d; j += 64) {
            int li = es - e0 + j;
            float s = (li < SC_CAP) ? sc_lds[li] : scores[rc2[es + j].x];
            m = fmaxf(m, s);
        }
#pragma unroll
        for (int off = 32; off > 0; off >>= 1)
            m = fmaxf(m, __shfl_down(m, off, 64));
        m = __shfl(m, 0, 64);

        float ssum = 0.0f;
        for (int j = lane; j < d; j += 64) {
            int li = es - e0 + j;
            float s = (li < SC_CAP) ? sc_lds[li] : scores[rc2[es + j].x];
            ssum += expf(s - m);
        }
#pragma unroll
        for (int off = 32; off > 0; off >>= 1)
            ssum += __shfl_down(ssum, off, 64);
        ssum = __shfl(ssum, 0, 64);

        for (int j = lane; j < d; j += 64) {
            int li = es - e0 + j;
            float s = (li < SC_CAP) ? sc_lds[li] : scores[rc2[es + j].x];
            float p = expf(s - m) / ssum;
            float logits = logf(p) - log1pf(-p);   // +inf when p==1 (d==1)
            int oe = rc2[es + j].x;
            float uu = u[oe];
            float L = logf(uu) - log1pf(-uu);
            float y = 1.0f / (1.0f + expf(-(logits + L)));
            bool hard = y > 0.5f;                  // ST forward value == y_hard
            int mm = hard ? (hv + 1) : edge_mask[oe];
            out_y[oe]      = hard ? 1.0f : 0.0f;
            out_mask[oe]   = (float)mm;
            out_causal[oe] = (mm > 0)   ?  s : 0.0f;
            out_spu[oe]    = (mm == -1) ? -s : 0.0f;
        }
    }
}

// ---------------------------------------------------------------------------
extern "C" void kernel_launch(void* const* d_in, const int* in_sizes, int n_in,
                              void* d_out, int out_size, void* d_ws, size_t ws_size,
                              hipStream_t stream) {
    const float* h_ptr = (const float*)d_in[0];
    const float* W1    = (const float*)d_in[1];
    const float* b1    = (const float*)d_in[2];
    const float* W2    = (const float*)d_in[3];
    const float* b2    = (const float*)d_in[4];
    const float* u     = (const float*)d_in[5];
    const int*   row   = (const int*)d_in[6];
    const int*   col   = (const int*)d_in[7];
    const int*   emask = (const int*)d_in[8];
    const int*   hier  = (const int*)d_in[9];

    float* out        = (float*)d_out;
    float* scores     = out;                        // [E]
    float* out_y      = out + (size_t)N_EDGES;      // [E]
    float* out_mask   = out + 2 * (size_t)N_EDGES;  // [E]
    float* out_causal = out + 3 * (size_t)N_EDGES;  // [E]
    float* out_spu    = out + 4 * (size_t)N_EDGES;  // [E]

    // workspace (4B units): P, Q first (16B align), rc2 (8B align), then ints
    float* P      = (float*)d_ws;
    float* Qm     = P + (size_t)N_NODES * HID;
    int2*  rc2    = (int2*)(Qm + (size_t)N_NODES * HID);   // [E] int2
    int*   deg    = (int*)(rc2 + N_EDGES);
    int*   cursor = deg + N_NODES;
    int*   offs   = cursor + N_NODES;               // [N_NODES+1]
    int*   part   = offs + N_NODES + 1;
    int*   totals = part + N_NODES;                 // [NCHUNK]

    hipMemsetAsync(deg, 0, (size_t)N_NODES * sizeof(int), stream);

    hipLaunchKernelGGL(gemm_hist, dim3(GEMM_BLOCKS + HIST_BLOCKS), dim3(256), 0, stream,
                       h_ptr, W1, b1, P, Qm, row, deg);

    hipLaunchKernelGGL(scan_part, dim3(NCHUNK), dim3(1024), 0, stream, deg, part, totals);
    hipLaunchKernelGGL(scan_apply, dim3(NCHUNK), dim3(1024), 0, stream,
                       part, totals, cursor, offs);
    hipLaunchKernelGGL(scatter_edges, dim3((N_EDGES + 255) / 256), dim3(256), 0, stream,
                       row, col, cursor, rc2);

    hipLaunchKernelGGL(fused_edge, dim3((N_NODES + ROWS_PER_BLOCK - 1) / ROWS_PER_BLOCK),
                       dim3(256), 0, stream,
                       P, Qm, W2, b2, rc2, offs, u, emask, hier,
                       scores, out_y, out_mask, out_causal, out_spu);
}